// Round 3
// baseline (12202.501 us; speedup 1.0000x reference)
//
#include <hip/hip_runtime.h>

typedef _Float16 h16;
typedef __attribute__((ext_vector_type(8))) _Float16 f16x8;
typedef __attribute__((ext_vector_type(4))) float f32x4;

#define B_ 128
#define T_ 256
#define H_ 512
#define S_ 32

__device__ __forceinline__ float fexp2(float x){ return __builtin_amdgcn_exp2f(x); }
__device__ __forceinline__ float frcp (float x){ return __builtin_amdgcn_rcpf(x); }
__device__ __forceinline__ float fsig (float x){ return frcp(1.f + fexp2(-1.44269504089f*x)); }
__device__ __forceinline__ float ftanh(float x){ return 1.f - 2.f*frcp(1.f + fexp2(2.88539008178f*x)); }

// ===========================================================================
// Persistent encoder: 256 WGs (1/CU) x 512 thr. WG = (dir, 4 hidden units).
// Weights LDS-resident (16 gate rows, interleaved r = gtype*4 + unit).
// Cell state in registers. Device-scope barrier per step (per-direction).
// ===========================================================================
struct EncP {
  const h16 *xpad, *Wih0, *Whh0, *Wih1, *Whh1;
  const float *b0, *b1;
  h16 *l1in, *encout;
  float *cdump;
  unsigned int* slots;
};

__device__ __forceinline__ void gridbar(unsigned int* slots, int myslot, int base,
                                        int n, unsigned int ep, int tid) {
  __syncthreads();  // all compute stores of this WG issued & drained
  if (tid == 0) {
    __builtin_amdgcn_fence(__ATOMIC_RELEASE, "agent");
    __hip_atomic_store(&slots[(size_t)myslot * 32], ep, __ATOMIC_RELAXED, __HIP_MEMORY_SCOPE_AGENT);
  }
  bool ok;
  do {
    ok = (tid < n) ? (__hip_atomic_load(&slots[(size_t)(base + tid) * 32],
                                        __ATOMIC_RELAXED, __HIP_MEMORY_SCOPE_AGENT) >= ep)
                   : true;
  } while (!__syncthreads_and(ok));
  if (tid == 0) __builtin_amdgcn_fence(__ATOMIC_ACQUIRE, "agent");
  __syncthreads();
}

__global__ __launch_bounds__(512, 1) void encoder_persist(EncP P) {
  const int wg = blockIdx.x, dir = wg >> 7;
  const int j0 = (wg & 127) << 2;          // hidden-unit base (4 units)
  const int tid = threadIdx.x, wid = tid >> 6, lane = tid & 63;
  const int col = lane & 15, rowg = lane >> 4;
  const int u = col & 3, gt = col >> 2;    // unit-in-WG, gate type of this lane's col
  const int m0 = wid << 4;                 // wave's 16-batch tile

  __shared__ h16 W[16][1544];              // 16 gate rows x (K + pad8)

  // stage interleaved weights: LDS row r holds global gate row (r>>2)*512 + j0 + (r&3)
  auto stage = [&](const h16* Wih, int Kx, const h16* Whh) {
    const int CX = Kx >> 3, CT = CX + 64;
    for (int i = tid; i < 16 * CT; i += 512) {
      const int r = i / CT, c = i - r * CT;
      const int grow = (r >> 2) * 512 + j0 + (r & 3);
      f16x8 v = (c < CX) ? *(const f16x8*)(Wih + (size_t)grow * Kx + (c << 3))
                         : *(const f16x8*)(Whh + (size_t)grow * 512 + ((c - CX) << 3));
      *(f16x8*)(&W[r][c << 3]) = v;
    }
  };
  auto pick = [&](float own, float p4, float p8, float p12, int x) {
    return x == 0 ? own : x == 1 ? p4 : x == 2 ? p8 : p12;
  };

  unsigned int ep = 0;
  float c0_ = 0.f, c1_ = 0.f, c2_ = 0.f, c3_ = 0.f;
  float h0, h1, h2, h3;

#define GATECOMB(av_, cvar, hvar, bias_)                                        \
  { float a_ = av_ + bias_;                                                     \
    float p4_ = __shfl_xor(a_, 4), p8_ = __shfl_xor(a_, 8), p12_ = __shfl_xor(a_, 12); \
    float iv = pick(a_, p4_, p8_, p12_, gt);                                    \
    float fv = pick(a_, p4_, p8_, p12_, gt ^ 1);                                \
    float gv = pick(a_, p4_, p8_, p12_, gt ^ 2);                                \
    float ov = pick(a_, p4_, p8_, p12_, gt ^ 3);                                \
    cvar = fsig(fv) * cvar + fsig(iv) * ftanh(gv);                              \
    hvar = fsig(ov) * ftanh(cvar); }

  // ================= phase 0 (layer 0) =================
  stage(P.Wih0 + (size_t)dir * 2048 * 32, 32, P.Whh0 + (size_t)dir * 2048 * 512);
  const float bias0 = P.b0[dir * 2048 + gt * 512 + j0 + u];
  __syncthreads();

  for (int i = 0; i < 256; ++i) {
    const int t = dir ? 255 - i : i;
    f32x4 acc = {0.f, 0.f, 0.f, 0.f};
    {  // x-part (K=32, one MFMA)
      f16x8 av = *(const f16x8*)(P.xpad + ((size_t)(m0 + col) * T_ + t) * 32 + rowg * 8);
      f16x8 bv = *(const f16x8*)(&W[col][rowg * 8]);
      acc = __builtin_amdgcn_mfma_f32_16x16x32_f16(av, bv, acc, 0, 0, 0);
    }
    if (i) {  // h-part (K=512)
      const int tp = dir ? t + 1 : t - 1;
      const h16* ah = P.l1in + ((size_t)tp * B_ + m0 + col) * 1024 + dir * 512 + rowg * 8;
      #pragma unroll
      for (int ks = 0; ks < 16; ++ks) {
        f16x8 av = *(const f16x8*)(ah + ks * 32);
        f16x8 bv = *(const f16x8*)(&W[col][32 + ks * 32 + rowg * 8]);
        acc = __builtin_amdgcn_mfma_f32_16x16x32_f16(av, bv, acc, 0, 0, 0);
      }
    }
    GATECOMB(acc[0], c0_, h0, bias0) GATECOMB(acc[1], c1_, h1, bias0)
    GATECOMB(acc[2], c2_, h2, bias0) GATECOMB(acc[3], c3_, h3, bias0)
    const float hw = (gt == 0) ? h0 : (gt == 1) ? h1 : (gt == 2) ? h2 : h3;
    const int bm = m0 + (rowg << 2) + gt;
    P.l1in[((size_t)t * B_ + bm) * 1024 + dir * 512 + j0 + u] = (h16)hw;
    gridbar(P.slots, wg, dir << 7, 128, ++ep, tid);
  }
  {  // dump layer-0 final cells for the decoder
    const float cw = (gt == 0) ? c0_ : (gt == 1) ? c1_ : (gt == 2) ? c2_ : c3_;
    const int bm = m0 + (rowg << 2) + gt;
    P.cdump[(size_t)dir * B_ * H_ + (size_t)bm * H_ + j0 + u] = cw;
  }
  gridbar(P.slots, wg, 0, 256, ++ep, tid);  // phase barrier (all WGs)

  // ================= phase 1 (layer 1) =================
  stage(P.Wih1 + (size_t)dir * 2048 * 1024, 1024, P.Whh1 + (size_t)dir * 2048 * 512);
  const float bias1 = P.b1[dir * 2048 + gt * 512 + j0 + u];
  c0_ = c1_ = c2_ = c3_ = 0.f;
  __syncthreads();

  for (int i = 0; i < 256; ++i) {
    const int t = dir ? 255 - i : i;
    f32x4 acc = {0.f, 0.f, 0.f, 0.f};
    const h16* ax = P.l1in + ((size_t)t * B_ + m0 + col) * 1024 + rowg * 8;
    #pragma unroll
    for (int ks = 0; ks < 32; ++ks) {  // x-part K=1024
      f16x8 av = *(const f16x8*)(ax + ks * 32);
      f16x8 bv = *(const f16x8*)(&W[col][ks * 32 + rowg * 8]);
      acc = __builtin_amdgcn_mfma_f32_16x16x32_f16(av, bv, acc, 0, 0, 0);
    }
    if (i) {  // h-part K=512
      const int tp = dir ? t + 1 : t - 1;
      const h16* ah = P.encout + ((size_t)(m0 + col) * T_ + tp) * 1024 + dir * 512 + rowg * 8;
      #pragma unroll
      for (int ks = 0; ks < 16; ++ks) {
        f16x8 av = *(const f16x8*)(ah + ks * 32);
        f16x8 bv = *(const f16x8*)(&W[col][1024 + ks * 32 + rowg * 8]);
        acc = __builtin_amdgcn_mfma_f32_16x16x32_f16(av, bv, acc, 0, 0, 0);
      }
    }
    GATECOMB(acc[0], c0_, h0, bias1) GATECOMB(acc[1], c1_, h1, bias1)
    GATECOMB(acc[2], c2_, h2, bias1) GATECOMB(acc[3], c3_, h3, bias1)
    const float hw = (gt == 0) ? h0 : (gt == 1) ? h1 : (gt == 2) ? h2 : h3;
    const int bm = m0 + (rowg << 2) + gt;
    P.encout[((size_t)bm * T_ + t) * 1024 + dir * 512 + j0 + u] = (h16)hw;
    gridbar(P.slots, wg, dir << 7, 128, ++ep, tid);
  }
#undef GATECOMB
}

// ---------------------------------------------------------------------------
// Decoder LSTM step (unchanged from round 1).
// ---------------------------------------------------------------------------
struct StepArgs {
  const h16* X;  int sx; int Kx;
  const h16* Wih;
  const h16* Hp; int sh;
  const h16* Whh;
  const float* bias;
  float* C;
  h16* Hn; int shn;
};

__global__ __launch_bounds__(256) void lstm_step(StepArgs A) {
  const int m0   = (blockIdx.x >> 5) << 4;
  const int j0   = (blockIdx.x & 31) << 4;
  const int wid  = threadIdx.x >> 6;
  const int lane = threadIdx.x & 63;
  const int r = lane & 15, g = lane >> 4;
  const int n0 = wid * H_ + j0;

  f32x4 acc = {0.f, 0.f, 0.f, 0.f};
  {
    const h16* xp = A.X   + (size_t)(m0 + r) * A.sx + g * 8;
    const h16* wp = A.Wih + (size_t)(n0 + r) * A.Kx + g * 8;
    for (int k = 0; k < A.Kx; k += 32) {
      f16x8 av = *(const f16x8*)(xp + k);
      f16x8 bv = *(const f16x8*)(wp + k);
      acc = __builtin_amdgcn_mfma_f32_16x16x32_f16(av, bv, acc, 0, 0, 0);
    }
  }
  {
    const h16* hp = A.Hp  + (size_t)(m0 + r) * A.sh + g * 8;
    const h16* wp = A.Whh + (size_t)(n0 + r) * H_   + g * 8;
    #pragma unroll
    for (int k = 0; k < H_; k += 32) {
      f16x8 av = *(const f16x8*)(hp + k);
      f16x8 bv = *(const f16x8*)(wp + k);
      acc = __builtin_amdgcn_mfma_f32_16x16x32_f16(av, bv, acc, 0, 0, 0);
    }
  }
  __shared__ float gtl[4][16][16];
  #pragma unroll
  for (int t = 0; t < 4; ++t) gtl[wid][g * 4 + t][r] = acc[t];
  __syncthreads();

  const int mi = threadIdx.x >> 4, ji = threadIdx.x & 15;
  const int jj = j0 + ji;
  float iv = gtl[0][mi][ji] + A.bias[jj];
  float fv = gtl[1][mi][ji] + A.bias[H_ + jj];
  float gv = gtl[2][mi][ji] + A.bias[2 * H_ + jj];
  float ov = gtl[3][mi][ji] + A.bias[3 * H_ + jj];
  float* cp = A.C + (size_t)(m0 + mi) * H_ + jj;
  float c = fsig(fv) * *cp + fsig(iv) * ftanh(gv);
  *cp = c;
  A.Hn[(size_t)(m0 + mi) * A.shn + jj] = (h16)(fsig(ov) * ftanh(c));
}

// ---------------------------------------------------------------------------
// Generic TN GEMM (unchanged).
// ---------------------------------------------------------------------------
__global__ __launch_bounds__(256) void gemm_tn(const h16* Am, int lda, const h16* Bm,
                                               const float* bias, void* Cout, int ldc,
                                               int K, int mode) {
  const int wid = threadIdx.x >> 6, lane = threadIdx.x & 63;
  const int r = lane & 15, g = lane >> 4;
  const int m0 = (blockIdx.x * 4 + wid) * 16;
  const int n0 = blockIdx.y * 64;
  f32x4 acc[4] = {{0,0,0,0},{0,0,0,0},{0,0,0,0},{0,0,0,0}};
  const h16* ap = Am + (size_t)(m0 + r) * lda + g * 8;
  const h16* bp = Bm + (size_t)(n0 + r) * K + g * 8;
  for (int k = 0; k < K; k += 32) {
    f16x8 av = *(const f16x8*)(ap + k);
    #pragma unroll
    for (int j = 0; j < 4; ++j) {
      f16x8 bv = *(const f16x8*)(bp + (size_t)j * 16 * K + k);
      acc[j] = __builtin_amdgcn_mfma_f32_16x16x32_f16(av, bv, acc[j], 0, 0, 0);
    }
  }
  #pragma unroll
  for (int j = 0; j < 4; ++j) {
    const int n = n0 + j * 16 + r;
    const float badd = bias ? bias[n] : 0.f;
    #pragma unroll
    for (int t = 0; t < 4; ++t) {
      const int m = m0 + g * 4 + t;
      float v = acc[j][t] + badd;
      if (mode == 2) v = ftanh(v);
      if (mode == 0) ((float*)Cout)[(size_t)m * ldc + n] = v;
      else           ((h16*)Cout) [(size_t)m * ldc + n] = (h16)v;
    }
  }
}

__global__ __launch_bounds__(256) void attn_score(const h16* __restrict__ Wv,
                                                  const float* __restrict__ qUa,
                                                  const float* __restrict__ Va,
                                                  float* __restrict__ score) {
  const int wid = threadIdx.x >> 6, lane = threadIdx.x & 63;
  const int wv = blockIdx.x * 4 + wid;
  const int m = wv >> 8, t = wv & 255;
  const h16*  wrow = Wv + (size_t)(m * 256 + t) * 512;
  const float* qrow = qUa + m * 512;
  float s = 0.f;
  #pragma unroll
  for (int i = 0; i < 8; ++i) {
    const int a = i * 64 + lane;
    s += ftanh((float)wrow[a] + qrow[a]) * Va[a];
  }
  #pragma unroll
  for (int o = 32; o; o >>= 1) s += __shfl_xor(s, o);
  if (lane == 0) score[m * 256 + t] = s;
}

__global__ __launch_bounds__(256) void attn_ctx(const float* __restrict__ score,
                                                const h16* __restrict__ enc,
                                                h16* __restrict__ xcat) {
  const int m = blockIdx.x, tid = threadIdx.x;
  __shared__ float red[256];
  __shared__ float wts[256];
  const float s = score[m * 256 + tid];
  red[tid] = s; __syncthreads();
  for (int o = 128; o; o >>= 1) { if (tid < o) red[tid] = fmaxf(red[tid], red[tid + o]); __syncthreads(); }
  const float mx = red[0]; __syncthreads();
  const float p = fexp2((s - mx) * 1.44269504089f);
  red[tid] = p; __syncthreads();
  for (int o = 128; o; o >>= 1) { if (tid < o) red[tid] += red[tid + o]; __syncthreads(); }
  wts[tid] = p * frcp(red[0]);
  __syncthreads();
  const h16* erow = enc + (size_t)m * 256 * 1024;
  #pragma unroll
  for (int i = 0; i < 4; ++i) {
    const int k = i * 256 + tid;
    float a0 = 0, a1 = 0, a2 = 0, a3 = 0;
    for (int t = 0; t < 256; t += 4) {
      a0 += wts[t    ] * (float)erow[(t    ) * 1024 + k];
      a1 += wts[t + 1] * (float)erow[(t + 1) * 1024 + k];
      a2 += wts[t + 2] * (float)erow[(t + 2) * 1024 + k];
      a3 += wts[t + 3] * (float)erow[(t + 3) * 1024 + k];
    }
    xcat[(size_t)m * 1056 + 2 + k] = (h16)((a0 + a1) + (a2 + a3));
  }
}

__global__ __launch_bounds__(256) void fc_out(const h16* __restrict__ h1,
                                              const float* __restrict__ fcW,
                                              const float* __restrict__ fcb,
                                              float* __restrict__ outcol,
                                              h16* __restrict__ xcat) {
  const int wid = threadIdx.x >> 6, lane = threadIdx.x & 63;
  const int wv = blockIdx.x * 4 + wid;
  #pragma unroll
  for (int j = 0; j < 4; ++j) {
    const int idx = wv * 4 + j;
    const int m = idx >> 1, o = idx & 1;
    float s = 0.f;
    #pragma unroll
    for (int i = 0; i < 8; ++i) {
      const int k = i * 64 + lane;
      s += (float)h1[m * 512 + k] * fcW[o * 512 + k];
    }
    #pragma unroll
    for (int off = 32; off; off >>= 1) s += __shfl_xor(s, off);
    if (lane == 0) {
      const float y = s + fcb[o];
      outcol[m * (S_ * 2) + o] = y;
      xcat[(size_t)m * 1056 + o] = (h16)y;
    }
  }
}

__global__ void convert_pad(const float* __restrict__ in, h16* __restrict__ out,
                            int rows, int Kin, int Kout) {
  const size_t i = (size_t)blockIdx.x * 256 + threadIdx.x;
  if (i >= (size_t)rows * Kout) return;
  const int r = (int)(i / Kout), k = (int)(i % Kout);
  out[i] = (k < Kin) ? (h16)in[(size_t)r * Kin + k] : (h16)0.f;
}

__global__ void y0_init(const float* __restrict__ x, h16* __restrict__ xcat) {
  const int tid = threadIdx.x;
  if (tid < 256) {
    const int m = tid >> 1, o = tid & 1;
    xcat[(size_t)m * 1056 + o] = (h16)x[(size_t)(m * T_ + (T_ - 1)) * 8 + o];
  }
}

extern "C" void kernel_launch(void* const* d_in, const int* in_sizes, int n_in,
                              void* d_out, int out_size, void* d_ws, size_t ws_size,
                              hipStream_t stream) {
  const float* x     = (const float*)d_in[0];
  const float* eWih0 = (const float*)d_in[1];
  const float* eWhh0 = (const float*)d_in[2];
  const float* eb0   = (const float*)d_in[3];
  const float* eWih1 = (const float*)d_in[4];
  const float* eWhh1 = (const float*)d_in[5];
  const float* eb1   = (const float*)d_in[6];
  const float* dWih0 = (const float*)d_in[7];
  const float* dWhh0 = (const float*)d_in[8];
  const float* db0   = (const float*)d_in[9];
  const float* dWih1 = (const float*)d_in[10];
  const float* dWhh1 = (const float*)d_in[11];
  const float* db1   = (const float*)d_in[12];
  const float* Wa    = (const float*)d_in[13];
  const float* Ua    = (const float*)d_in[14];
  const float* Va    = (const float*)d_in[15];
  const float* projW = (const float*)d_in[16];
  const float* projb = (const float*)d_in[17];
  const float* fcW   = (const float*)d_in[18];
  const float* fcb   = (const float*)d_in[19];
  float* out = (float*)d_out;

  size_t cur = 0;
  auto alloc = [&](size_t bytes) {
    void* p = (char*)d_ws + cur;
    cur += (bytes + 255) & ~(size_t)255;
    return p;
  };
  h16*  xpad   = (h16*) alloc((size_t)B_ * T_ * 32 * 2);
  h16*  l1in   = (h16*) alloc((size_t)T_ * B_ * 1024 * 2);   // layer-0 h history (T,B,2H)
  h16*  encout = (h16*) alloc((size_t)B_ * T_ * 1024 * 2);   // layer-1 h history (B,T,2H)
  h16*  WaV    = (h16*) alloc((size_t)B_ * T_ * H_ * 2);
  float* cdump = (float*)alloc((size_t)2 * B_ * H_ * 4);     // layer-0 final cells [dir][B][H]
  float* score = (float*)alloc((size_t)B_ * T_ * 4);
  float* qUa   = (float*)alloc((size_t)B_ * H_ * 4);
  h16*  xcat   = (h16*) alloc((size_t)B_ * 1056 * 2);
  h16*  dh0    = (h16*) alloc((size_t)2 * B_ * H_ * 2);
  h16*  dh1    = (h16*) alloc((size_t)2 * B_ * H_ * 2);
  unsigned int* slots = (unsigned int*)alloc((size_t)256 * 32 * 4);
  h16*  bWih0  = (h16*) alloc((size_t)2 * 2048 * 32 * 2);
  h16*  bWhh0  = (h16*) alloc((size_t)2 * 2048 * 512 * 2);
  h16*  bWih1  = (h16*) alloc((size_t)2 * 2048 * 1024 * 2);
  h16*  bWhh1  = (h16*) alloc((size_t)2 * 2048 * 512 * 2);
  h16*  bdWih0 = (h16*) alloc((size_t)2048 * 1056 * 2);
  h16*  bdWhh0 = (h16*) alloc((size_t)2048 * 512 * 2);
  h16*  bdWih1 = (h16*) alloc((size_t)2048 * 512 * 2);
  h16*  bdWhh1 = (h16*) alloc((size_t)2048 * 512 * 2);
  h16*  bWa    = (h16*) alloc((size_t)512 * 1024 * 2);
  h16*  bUa    = (h16*) alloc((size_t)512 * 512 * 2);
  h16*  bprojW = (h16*) alloc((size_t)512 * 512 * 2);
  if (cur > ws_size) return;

  (void)hipMemsetAsync(slots, 0, (size_t)256 * 32 * 4, stream);
  (void)hipMemsetAsync(xcat, 0, (size_t)B_ * 1056 * 2, stream);

  auto conv = [&](const float* in, h16* o, int rows, int kin, int kout) {
    const size_t total = (size_t)rows * kout;
    convert_pad<<<dim3((unsigned)((total + 255) / 256)), dim3(256), 0, stream>>>(in, o, rows, kin, kout);
  };
  conv(x,     xpad,   B_ * T_,  8,    32);
  conv(eWih0, bWih0,  2 * 2048, 8,    32);
  conv(eWhh0, bWhh0,  2 * 2048, 512,  512);
  conv(eWih1, bWih1,  2 * 2048, 1024, 1024);
  conv(eWhh1, bWhh1,  2 * 2048, 512,  512);
  conv(dWih0, bdWih0, 2048,     1026, 1056);
  conv(dWhh0, bdWhh0, 2048,     512,  512);
  conv(dWih1, bdWih1, 2048,     512,  512);
  conv(dWhh1, bdWhh1, 2048,     512,  512);
  conv(Wa,    bWa,    512,      1024, 1024);
  conv(Ua,    bUa,    512,      512,  512);
  conv(projW, bprojW, 512,      512,  512);

  // ---- whole encoder: ONE persistent kernel ----
  EncP P;
  P.xpad = xpad; P.Wih0 = bWih0; P.Whh0 = bWhh0; P.Wih1 = bWih1; P.Whh1 = bWhh1;
  P.b0 = eb0; P.b1 = eb1; P.l1in = l1in; P.encout = encout; P.cdump = cdump; P.slots = slots;
  encoder_persist<<<dim3(256), dim3(512), 0, stream>>>(P);

  // ---- Wa_vals = enc_out @ Wa^T ----
  gemm_tn<<<dim3(B_ * T_ / 64, 8), dim3(256), 0, stream>>>(encout, 1024, bWa, nullptr, WaV, 512, 1024, 1);
  // ---- decoder h init ----
  gemm_tn<<<dim3(B_ / 64, 8), dim3(256), 0, stream>>>(l1in + (size_t)(T_ - 1) * B_ * 1024, 1024,
                                                      bprojW, projb, dh0, 512, 512, 2);
  gemm_tn<<<dim3(B_ / 64, 8), dim3(256), 0, stream>>>(l1in + 512, 1024,
                                                      bprojW, projb, dh1, 512, 512, 2);
  y0_init<<<dim3(1), dim3(256), 0, stream>>>(x, xcat);

  float* dc0 = cdump;               // layer-0 fwd final c
  float* dc1 = cdump + B_ * H_;     // layer-0 bwd final c

  int pp = 0;
  for (int s = 0; s < S_; ++s) {
    const int nx = pp ^ 1;
    h16* h0c = dh0 + (size_t)pp * B_ * H_;  h16* h0n = dh0 + (size_t)nx * B_ * H_;
    h16* h1c = dh1 + (size_t)pp * B_ * H_;  h16* h1n = dh1 + (size_t)nx * B_ * H_;

    gemm_tn<<<dim3(2, 8), dim3(256), 0, stream>>>(h1c, 512, bUa, nullptr, qUa, 512, 512, 0);
    attn_score<<<dim3(B_ * T_ / 4), dim3(256), 0, stream>>>(WaV, qUa, Va, score);
    attn_ctx<<<dim3(B_), dim3(256), 0, stream>>>(score, encout, xcat);

    StepArgs a{};
    a.X = xcat;  a.sx = 1056;  a.Kx = 1056;  a.Wih = bdWih0;
    a.Hp = h0c;  a.sh = 512;   a.Whh = bdWhh0;  a.bias = db0;
    a.C = dc0;   a.Hn = h0n;   a.shn = 512;
    lstm_step<<<dim3(256), dim3(256), 0, stream>>>(a);

    StepArgs a2{};
    a2.X = h0n;  a2.sx = 512;  a2.Kx = 512;  a2.Wih = bdWih1;
    a2.Hp = h1c; a2.sh = 512;  a2.Whh = bdWhh1;  a2.bias = db1;
    a2.C = dc1;  a2.Hn = h1n;  a2.shn = 512;
    lstm_step<<<dim3(256), dim3(256), 0, stream>>>(a2);

    fc_out<<<dim3(16), dim3(256), 0, stream>>>(h1n, fcW, fcb, out + s * 2, xcat);
    pp = nx;
  }
}

// Round 4
// 10749.102 us; speedup vs baseline: 1.1352x; 1.1352x over previous
//
#include <hip/hip_runtime.h>

typedef _Float16 h16;
typedef __attribute__((ext_vector_type(8))) _Float16 f16x8;
typedef __attribute__((ext_vector_type(4))) float f32x4;
typedef unsigned long long u64;
typedef unsigned int u32;
typedef unsigned short u16;

#define B_ 128
#define T_ 256
#define H_ 512
#define S_ 32
#define MFMA __builtin_amdgcn_mfma_f32_16x16x32_f16

__device__ __forceinline__ float fexp2(float x){ return __builtin_amdgcn_exp2f(x); }
__device__ __forceinline__ float frcp (float x){ return __builtin_amdgcn_rcpf(x); }
__device__ __forceinline__ float fsig (float x){ return frcp(1.f + fexp2(-1.44269504089f*x)); }
__device__ __forceinline__ float ftanh(float x){ return 1.f - 2.f*frcp(1.f + fexp2(2.88539008178f*x)); }

// ---- device-coherent (LLC-point, L2-bypass) access helpers: relaxed agent atomics ----
__device__ __forceinline__ f16x8 ld16_coh(const h16* p) {
  u64 q0 = __hip_atomic_load((const u64*)p,     __ATOMIC_RELAXED, __HIP_MEMORY_SCOPE_AGENT);
  u64 q1 = __hip_atomic_load((const u64*)p + 1, __ATOMIC_RELAXED, __HIP_MEMORY_SCOPE_AGENT);
  u64 a[2] = {q0, q1};
  f16x8 v; __builtin_memcpy(&v, a, 16);
  return v;
}
__device__ __forceinline__ float ld4f_coh(const float* p) {
  u32 b = __hip_atomic_load((const u32*)p, __ATOMIC_RELAXED, __HIP_MEMORY_SCOPE_AGENT);
  float v; __builtin_memcpy(&v, &b, 4);
  return v;
}
__device__ __forceinline__ float ld2h_coh(const h16* p) {
  u16 b = __hip_atomic_load((const u16*)p, __ATOMIC_RELAXED, __HIP_MEMORY_SCOPE_AGENT);
  h16 v; __builtin_memcpy(&v, &b, 2);
  return (float)v;
}
__device__ __forceinline__ void st2_coh(h16* p, h16 v) {
  u16 b; __builtin_memcpy(&b, &v, 2);
  __hip_atomic_store((u16*)p, b, __ATOMIC_RELAXED, __HIP_MEMORY_SCOPE_AGENT);
}
__device__ __forceinline__ void st4_coh(float* p, float v) {
  u32 b; __builtin_memcpy(&b, &v, 4);
  __hip_atomic_store((u32*)p, b, __ATOMIC_RELAXED, __HIP_MEMORY_SCOPE_AGENT);
}

// Fence-free grid barrier. Correctness: all data crossing this barrier is written
// with sc1 (L2-bypass) atomics; __syncthreads() drains each wave's vmcnt (compiler
// emits s_waitcnt vmcnt(0) before s_barrier), so stores are LLC-visible before the
// flag store. No buffer_wbl2/buffer_inv -> L2 stays hot for cached stable data.
__device__ __forceinline__ void gridbar(u32* slots, int myslot, int base,
                                        int n, u32 ep, int tid) {
  __syncthreads();
  if (tid == 0)
    __hip_atomic_store(&slots[(size_t)myslot * 32], ep, __ATOMIC_RELAXED, __HIP_MEMORY_SCOPE_AGENT);
  bool ok;
  do {
    ok = (tid < n) ? (__hip_atomic_load(&slots[(size_t)(base + tid) * 32],
                                        __ATOMIC_RELAXED, __HIP_MEMORY_SCOPE_AGENT) >= ep)
                   : true;
  } while (!__syncthreads_and(ok));
  __syncthreads();
}

// ===========================================================================
// Persistent encoder: 256 WGs x 512 thr. WG = (dir, 4 hidden units).
// Weights LDS-resident; cell state in registers; recurrent h via sc1 atomics.
// ===========================================================================
struct EncP {
  const h16 *xpad, *Wih0, *Whh0, *Wih1, *Whh1;
  const float *b0, *b1;
  h16 *l1in, *encout;
  float *cdump;
  u32* slots;
};

__global__ __launch_bounds__(512, 1) void encoder_persist(EncP P) {
  const int wg = blockIdx.x, dir = wg >> 7;
  const int j0 = (wg & 127) << 2;
  const int tid = threadIdx.x, wid = tid >> 6, lane = tid & 63;
  const int col = lane & 15, rowg = lane >> 4;
  const int u = col & 3, gt = col >> 2;
  const int m0 = wid << 4;

  __shared__ h16 W[16][1544];

  auto stage = [&](const h16* Wih, int Kx, const h16* Whh) {
    const int CX = Kx >> 3, CT = CX + 64;
    for (int i = tid; i < 16 * CT; i += 512) {
      const int r = i / CT, c = i - r * CT;
      const int grow = (r >> 2) * 512 + j0 + (r & 3);
      f16x8 v = (c < CX) ? *(const f16x8*)(Wih + (size_t)grow * Kx + (c << 3))
                         : *(const f16x8*)(Whh + (size_t)grow * 512 + ((c - CX) << 3));
      *(f16x8*)(&W[r][c << 3]) = v;
    }
  };
  auto pick = [&](float own, float p4, float p8, float p12, int x) {
    return x == 0 ? own : x == 1 ? p4 : x == 2 ? p8 : p12;
  };

  u32 ep = 0;
  float c0_ = 0.f, c1_ = 0.f, c2_ = 0.f, c3_ = 0.f;
  float h0, h1, h2, h3;

#define GATECOMB(av_, cvar, hvar, bias_)                                        \
  { float a_ = av_ + bias_;                                                     \
    float p4_ = __shfl_xor(a_, 4), p8_ = __shfl_xor(a_, 8), p12_ = __shfl_xor(a_, 12); \
    float iv = pick(a_, p4_, p8_, p12_, gt);                                    \
    float fv = pick(a_, p4_, p8_, p12_, gt ^ 1);                                \
    float gv = pick(a_, p4_, p8_, p12_, gt ^ 2);                                \
    float ov = pick(a_, p4_, p8_, p12_, gt ^ 3);                                \
    cvar = fsig(fv) * cvar + fsig(iv) * ftanh(gv);                              \
    hvar = fsig(ov) * ftanh(cvar); }

  // ================= phase 0 (layer 0) =================
  stage(P.Wih0 + (size_t)dir * 2048 * 32, 32, P.Whh0 + (size_t)dir * 2048 * 512);
  const float bias0 = P.b0[dir * 2048 + gt * 512 + j0 + u];
  __syncthreads();

  for (int i = 0; i < 256; ++i) {
    const int t = dir ? 255 - i : i;
    f32x4 acc = {0.f, 0.f, 0.f, 0.f};
    {
      f16x8 av = *(const f16x8*)(P.xpad + ((size_t)(m0 + col) * T_ + t) * 32 + rowg * 8);
      f16x8 bv = *(const f16x8*)(&W[col][rowg * 8]);
      acc = MFMA(av, bv, acc, 0, 0, 0);
    }
    if (i) {
      const int tp = dir ? t + 1 : t - 1;
      const h16* ah = P.l1in + ((size_t)tp * B_ + m0 + col) * 1024 + dir * 512 + rowg * 8;
      #pragma unroll
      for (int ks = 0; ks < 16; ++ks) {
        f16x8 av = ld16_coh(ah + ks * 32);
        f16x8 bv = *(const f16x8*)(&W[col][32 + ks * 32 + rowg * 8]);
        acc = MFMA(av, bv, acc, 0, 0, 0);
      }
    }
    GATECOMB(acc[0], c0_, h0, bias0) GATECOMB(acc[1], c1_, h1, bias0)
    GATECOMB(acc[2], c2_, h2, bias0) GATECOMB(acc[3], c3_, h3, bias0)
    const float hw = (gt == 0) ? h0 : (gt == 1) ? h1 : (gt == 2) ? h2 : h3;
    const int bm = m0 + (rowg << 2) + gt;
    st2_coh(&P.l1in[((size_t)t * B_ + bm) * 1024 + dir * 512 + j0 + u], (h16)hw);
    gridbar(P.slots, wg, dir << 7, 128, ++ep, tid);
  }
  {
    const float cw = (gt == 0) ? c0_ : (gt == 1) ? c1_ : (gt == 2) ? c2_ : c3_;
    const int bm = m0 + (rowg << 2) + gt;
    P.cdump[(size_t)dir * B_ * H_ + (size_t)bm * H_ + j0 + u] = cw;  // read post-kernel
  }
  gridbar(P.slots, wg, 0, 256, ++ep, tid);  // phase barrier

  // ================= phase 1 (layer 1) =================
  stage(P.Wih1 + (size_t)dir * 2048 * 1024, 1024, P.Whh1 + (size_t)dir * 2048 * 512);
  const float bias1 = P.b1[dir * 2048 + gt * 512 + j0 + u];
  c0_ = c1_ = c2_ = c3_ = 0.f;
  __syncthreads();

  for (int i = 0; i < 256; ++i) {
    const int t = dir ? 255 - i : i;
    f32x4 acc = {0.f, 0.f, 0.f, 0.f};
    const h16* ax = P.l1in + ((size_t)t * B_ + m0 + col) * 1024 + rowg * 8;
    #pragma unroll
    for (int ks = 0; ks < 32; ++ks) {  // stable input: cached loads, L2-hot
      f16x8 av = *(const f16x8*)(ax + ks * 32);
      f16x8 bv = *(const f16x8*)(&W[col][ks * 32 + rowg * 8]);
      acc = MFMA(av, bv, acc, 0, 0, 0);
    }
    if (i) {
      const int tp = dir ? t + 1 : t - 1;
      const h16* ah = P.encout + ((size_t)(m0 + col) * T_ + tp) * 1024 + dir * 512 + rowg * 8;
      #pragma unroll
      for (int ks = 0; ks < 16; ++ks) {
        f16x8 av = ld16_coh(ah + ks * 32);
        f16x8 bv = *(const f16x8*)(&W[col][1024 + ks * 32 + rowg * 8]);
        acc = MFMA(av, bv, acc, 0, 0, 0);
      }
    }
    GATECOMB(acc[0], c0_, h0, bias1) GATECOMB(acc[1], c1_, h1, bias1)
    GATECOMB(acc[2], c2_, h2, bias1) GATECOMB(acc[3], c3_, h3, bias1)
    const float hw = (gt == 0) ? h0 : (gt == 1) ? h1 : (gt == 2) ? h2 : h3;
    const int bm = m0 + (rowg << 2) + gt;
    st2_coh(&P.encout[((size_t)bm * T_ + t) * 1024 + dir * 512 + j0 + u], (h16)hw);
    gridbar(P.slots, wg, dir << 7, 128, ++ep, tid);
  }
#undef GATECOMB
}

// ===========================================================================
// Persistent decoder: 256 WGs x 512 thr, all 32 steps, 5 grid barriers/step.
// WG owns (m-tile, unit-tile) for both LSTMs; c-states in registers.
// ===========================================================================
struct DecP {
  const h16 *bUa, *WaV, *enc, *bdWih0, *bdWhh0, *bdWih1, *bdWhh1;
  const float *Va, *db0, *db1, *fcW, *fcb, *cdump;
  float *qUa, *score, *out;
  h16 *xcat, *dh0, *dh1;
  u32* slots;
};

__global__ __launch_bounds__(512, 1) void decoder_persist(DecP D) {
  const int wg = blockIdx.x, tid = threadIdx.x;
  const int wid = tid >> 6, lane = tid & 63;
  const int col = lane & 15, rowg = lane >> 4;
  const int gw = wg * 8 + wid;
  const int mt = wg >> 5, ut = wg & 31;
  const int mi = tid >> 4, ji = tid & 15;

  __shared__ h16 Ast[16][1576];
  __shared__ float gtl[4][16][16];
  __shared__ float sred[256], swts[256];

  float c0r = 0.f, c1r = 0.f;
  if (tid < 256) {
    c0r = D.cdump[(size_t)(mt * 16 + mi) * 512 + ut * 16 + ji];
    c1r = D.cdump[(size_t)B_ * H_ + (size_t)(mt * 16 + mi) * 512 + ut * 16 + ji];
  }
  u32 ep = 0;

  for (int s = 0; s < S_; ++s) {
    const int par = s & 1;
    const h16* h1c = D.dh1 + (size_t)par * B_ * H_;
    h16* h1n = D.dh1 + (size_t)(par ^ 1) * B_ * H_;
    const h16* h0c = D.dh0 + (size_t)par * B_ * H_;
    h16* h0n = D.dh0 + (size_t)(par ^ 1) * B_ * H_;

    // ---- S1: qUa = h1c @ Ua^T   ||   S6: y_{s-1} = fc(h1c) ----
    if (gw < 256) {
      const int qmt = gw >> 5, qnt = gw & 31;
      f32x4 acc = {0, 0, 0, 0};
      const h16* ap = h1c + (size_t)(qmt * 16 + col) * 512 + rowg * 8;
      const h16* bp = D.bUa + (size_t)(qnt * 16 + col) * 512 + rowg * 8;
      #pragma unroll
      for (int kc = 0; kc < 16; ++kc) {
        f16x8 av = ld16_coh(ap + kc * 32);
        f16x8 bv = *(const f16x8*)(bp + kc * 32);
        acc = MFMA(av, bv, acc, 0, 0, 0);
      }
      #pragma unroll
      for (int t2 = 0; t2 < 4; ++t2)
        st4_coh(D.qUa + (size_t)(qmt * 16 + rowg * 4 + t2) * 512 + qnt * 16 + col, acc[t2]);
    } else if (gw < 512 && s > 0) {
      const int idx = gw - 256, m = idx >> 1, o = idx & 1;
      float sum = 0.f;
      #pragma unroll
      for (int i2 = 0; i2 < 8; ++i2) {
        const int k = i2 * 64 + lane;
        sum += ld2h_coh(h1c + (size_t)m * 512 + k) * D.fcW[o * 512 + k];
      }
      #pragma unroll
      for (int o2 = 32; o2; o2 >>= 1) sum += __shfl_xor(sum, o2);
      if (lane == 0) {
        const float y = sum + D.fcb[o];
        D.out[(size_t)m * (S_ * 2) + (s - 1) * 2 + o] = y;
        st2_coh(D.xcat + (size_t)m * 1056 + o, (h16)y);
      }
    }
    gridbar(D.slots, wg, 0, 256, ++ep, tid);

    // ---- S2: score[m,t] = sum_a tanh(WaV + qUa) * Va ----
    {
      const int m = gw >> 4, tg = gw & 15;
      float q[8], va[8];
      #pragma unroll
      for (int i2 = 0; i2 < 8; ++i2) {
        q[i2] = ld4f_coh(D.qUa + (size_t)m * 512 + i2 * 64 + lane);
        va[i2] = D.Va[i2 * 64 + lane];
      }
      for (int tt = 0; tt < 16; ++tt) {
        const int t = tg * 16 + tt;
        const h16* wrow = D.WaV + ((size_t)m * 256 + t) * 512;
        float ssum = 0.f;
        #pragma unroll
        for (int i2 = 0; i2 < 8; ++i2)
          ssum += ftanh((float)wrow[i2 * 64 + lane] + q[i2]) * va[i2];
        #pragma unroll
        for (int o2 = 32; o2; o2 >>= 1) ssum += __shfl_xor(ssum, o2);
        if (lane == 0) st4_coh(D.score + (size_t)m * 256 + t, ssum);
      }
    }
    gridbar(D.slots, wg, 0, 256, ++ep, tid);

    // ---- S3: softmax over t + ctx z -> xcat[2..1026) ----
    if (wg < 128) {
      const int m = wg;
      const float sv = (tid < 256) ? ld4f_coh(D.score + (size_t)m * 256 + tid) : -1e30f;
      if (tid < 256) sred[tid] = sv;
      __syncthreads();
      for (int o2 = 128; o2; o2 >>= 1) { if (tid < o2) sred[tid] = fmaxf(sred[tid], sred[tid + o2]); __syncthreads(); }
      const float mx = sred[0]; __syncthreads();
      const float p = (tid < 256) ? fexp2((sv - mx) * 1.44269504089f) : 0.f;
      if (tid < 256) sred[tid] = p;
      __syncthreads();
      for (int o2 = 128; o2; o2 >>= 1) { if (tid < o2) sred[tid] += sred[tid + o2]; __syncthreads(); }
      if (tid < 256) swts[tid] = p * frcp(sred[0]);
      __syncthreads();
      const h16* erow = D.enc + (size_t)m * 256 * 1024;
      #pragma unroll
      for (int half = 0; half < 2; ++half) {
        const int k = tid + half * 512;
        float a0 = 0, a1 = 0, a2 = 0, a3 = 0;
        for (int t = 0; t < 256; t += 4) {
          a0 += swts[t    ] * (float)erow[(t    ) * 1024 + k];
          a1 += swts[t + 1] * (float)erow[(t + 1) * 1024 + k];
          a2 += swts[t + 2] * (float)erow[(t + 2) * 1024 + k];
          a3 += swts[t + 3] * (float)erow[(t + 3) * 1024 + k];
        }
        st2_coh(D.xcat + (size_t)m * 1056 + 2 + k, (h16)((a0 + a1) + (a2 + a3)));
      }
    }
    gridbar(D.slots, wg, 0, 256, ++ep, tid);

    // ---- S4: lstm0 (K = 1056 xcat + 512 h0c) ----
    {
      for (int i2 = tid; i2 < 16 * 196; i2 += 512) {
        const int r = i2 / 196, c = i2 - r * 196;
        f16x8 v = (c < 132) ? ld16_coh(D.xcat + (size_t)(mt * 16 + r) * 1056 + c * 8)
                            : ld16_coh(h0c + (size_t)(mt * 16 + r) * 512 + (c - 132) * 8);
        *(f16x8*)&Ast[r][c * 8] = v;
      }
      __syncthreads();
      if (wid < 4) {
        const int n = wid * 512 + ut * 16 + col;
        f32x4 acc = {0, 0, 0, 0};
        const h16* w1 = D.bdWih0 + (size_t)n * 1056 + rowg * 8;
        const h16* w2 = D.bdWhh0 + (size_t)n * 512 + rowg * 8;
        #pragma unroll
        for (int kc = 0; kc < 33; ++kc) {
          f16x8 av = *(const f16x8*)&Ast[col][kc * 32 + rowg * 8];
          f16x8 bv = *(const f16x8*)(w1 + kc * 32);
          acc = MFMA(av, bv, acc, 0, 0, 0);
        }
        #pragma unroll
        for (int kc = 0; kc < 16; ++kc) {
          f16x8 av = *(const f16x8*)&Ast[col][1056 + kc * 32 + rowg * 8];
          f16x8 bv = *(const f16x8*)(w2 + kc * 32);
          acc = MFMA(av, bv, acc, 0, 0, 0);
        }
        #pragma unroll
        for (int t2 = 0; t2 < 4; ++t2) gtl[wid][rowg * 4 + t2][col] = acc[t2];
      }
      __syncthreads();
      if (tid < 256) {
        const int jj = ut * 16 + ji;
        const float iv = gtl[0][mi][ji] + D.db0[jj];
        const float fv = gtl[1][mi][ji] + D.db0[512 + jj];
        const float gv = gtl[2][mi][ji] + D.db0[1024 + jj];
        const float ov = gtl[3][mi][ji] + D.db0[1536 + jj];
        c0r = fsig(fv) * c0r + fsig(iv) * ftanh(gv);
        st2_coh(h0n + (size_t)(mt * 16 + mi) * 512 + jj, (h16)(fsig(ov) * ftanh(c0r)));
      }
    }
    gridbar(D.slots, wg, 0, 256, ++ep, tid);

    // ---- S5: lstm1 (K = 512 h0n + 512 h1c) ----
    {
      for (int i2 = tid; i2 < 16 * 128; i2 += 512) {
        const int r = i2 >> 7, c = i2 & 127;
        f16x8 v = (c < 64) ? ld16_coh(h0n + (size_t)(mt * 16 + r) * 512 + c * 8)
                           : ld16_coh(h1c + (size_t)(mt * 16 + r) * 512 + (c - 64) * 8);
        *(f16x8*)&Ast[r][c * 8] = v;
      }
      __syncthreads();
      if (wid < 4) {
        const int n = wid * 512 + ut * 16 + col;
        f32x4 acc = {0, 0, 0, 0};
        const h16* w1 = D.bdWih1 + (size_t)n * 512 + rowg * 8;
        const h16* w2 = D.bdWhh1 + (size_t)n * 512 + rowg * 8;
        #pragma unroll
        for (int kc = 0; kc < 16; ++kc) {
          f16x8 av = *(const f16x8*)&Ast[col][kc * 32 + rowg * 8];
          f16x8 bv = *(const f16x8*)(w1 + kc * 32);
          acc = MFMA(av, bv, acc, 0, 0, 0);
        }
        #pragma unroll
        for (int kc = 0; kc < 16; ++kc) {
          f16x8 av = *(const f16x8*)&Ast[col][512 + kc * 32 + rowg * 8];
          f16x8 bv = *(const f16x8*)(w2 + kc * 32);
          acc = MFMA(av, bv, acc, 0, 0, 0);
        }
        #pragma unroll
        for (int t2 = 0; t2 < 4; ++t2) gtl[wid][rowg * 4 + t2][col] = acc[t2];
      }
      __syncthreads();
      if (tid < 256) {
        const int jj = ut * 16 + ji;
        const float iv = gtl[0][mi][ji] + D.db1[jj];
        const float fv = gtl[1][mi][ji] + D.db1[512 + jj];
        const float gv = gtl[2][mi][ji] + D.db1[1024 + jj];
        const float ov = gtl[3][mi][ji] + D.db1[1536 + jj];
        c1r = fsig(fv) * c1r + fsig(iv) * ftanh(gv);
        st2_coh(h1n + (size_t)(mt * 16 + mi) * 512 + jj, (h16)(fsig(ov) * ftanh(c1r)));
      }
    }
    gridbar(D.slots, wg, 0, 256, ++ep, tid);
  }

  // ---- final fc: y_31 from dh1[0] ----
  if (gw < 256) {
    const int m = gw >> 1, o = gw & 1;
    const h16* h1f = D.dh1;  // after s=31 (par=1), h1n = dh1[0]
    float sum = 0.f;
    #pragma unroll
    for (int i2 = 0; i2 < 8; ++i2) {
      const int k = i2 * 64 + lane;
      sum += ld2h_coh(h1f + (size_t)m * 512 + k) * D.fcW[o * 512 + k];
    }
    #pragma unroll
    for (int o2 = 32; o2; o2 >>= 1) sum += __shfl_xor(sum, o2);
    if (lane == 0) D.out[(size_t)m * (S_ * 2) + (S_ - 1) * 2 + o] = sum + D.fcb[o];
  }
}

// ---------------------------------------------------------------------------
// Generic TN GEMM (WaV + proj init).
// ---------------------------------------------------------------------------
__global__ __launch_bounds__(256) void gemm_tn(const h16* Am, int lda, const h16* Bm,
                                               const float* bias, void* Cout, int ldc,
                                               int K, int mode) {
  const int wid = threadIdx.x >> 6, lane = threadIdx.x & 63;
  const int r = lane & 15, g = lane >> 4;
  const int m0 = (blockIdx.x * 4 + wid) * 16;
  const int n0 = blockIdx.y * 64;
  f32x4 acc[4] = {{0,0,0,0},{0,0,0,0},{0,0,0,0},{0,0,0,0}};
  const h16* ap = Am + (size_t)(m0 + r) * lda + g * 8;
  const h16* bp = Bm + (size_t)(n0 + r) * K + g * 8;
  for (int k = 0; k < K; k += 32) {
    f16x8 av = *(const f16x8*)(ap + k);
    #pragma unroll
    for (int j = 0; j < 4; ++j) {
      f16x8 bv = *(const f16x8*)(bp + (size_t)j * 16 * K + k);
      acc[j] = MFMA(av, bv, acc[j], 0, 0, 0);
    }
  }
  #pragma unroll
  for (int j = 0; j < 4; ++j) {
    const int n = n0 + j * 16 + r;
    const float badd = bias ? bias[n] : 0.f;
    #pragma unroll
    for (int t = 0; t < 4; ++t) {
      const int m = m0 + g * 4 + t;
      float v = acc[j][t] + badd;
      if (mode == 2) v = ftanh(v);
      if (mode == 0) ((float*)Cout)[(size_t)m * ldc + n] = v;
      else           ((h16*)Cout) [(size_t)m * ldc + n] = (h16)v;
    }
  }
}

__global__ void convert_pad(const float* __restrict__ in, h16* __restrict__ out,
                            int rows, int Kin, int Kout) {
  const size_t i = (size_t)blockIdx.x * 256 + threadIdx.x;
  if (i >= (size_t)rows * Kout) return;
  const int r = (int)(i / Kout), k = (int)(i % Kout);
  out[i] = (k < Kin) ? (h16)in[(size_t)r * Kin + k] : (h16)0.f;
}

__global__ void y0_init(const float* __restrict__ x, h16* __restrict__ xcat) {
  const int tid = threadIdx.x;
  if (tid < 256) {
    const int m = tid >> 1, o = tid & 1;
    xcat[(size_t)m * 1056 + o] = (h16)x[(size_t)(m * T_ + (T_ - 1)) * 8 + o];
  }
}

extern "C" void kernel_launch(void* const* d_in, const int* in_sizes, int n_in,
                              void* d_out, int out_size, void* d_ws, size_t ws_size,
                              hipStream_t stream) {
  const float* x     = (const float*)d_in[0];
  const float* eWih0 = (const float*)d_in[1];
  const float* eWhh0 = (const float*)d_in[2];
  const float* eb0   = (const float*)d_in[3];
  const float* eWih1 = (const float*)d_in[4];
  const float* eWhh1 = (const float*)d_in[5];
  const float* eb1   = (const float*)d_in[6];
  const float* dWih0 = (const float*)d_in[7];
  const float* dWhh0 = (const float*)d_in[8];
  const float* db0   = (const float*)d_in[9];
  const float* dWih1 = (const float*)d_in[10];
  const float* dWhh1 = (const float*)d_in[11];
  const float* db1   = (const float*)d_in[12];
  const float* Wa    = (const float*)d_in[13];
  const float* Ua    = (const float*)d_in[14];
  const float* Va    = (const float*)d_in[15];
  const float* projW = (const float*)d_in[16];
  const float* projb = (const float*)d_in[17];
  const float* fcW   = (const float*)d_in[18];
  const float* fcb   = (const float*)d_in[19];
  float* out = (float*)d_out;

  size_t cur = 0;
  auto alloc = [&](size_t bytes) {
    void* p = (char*)d_ws + cur;
    cur += (bytes + 255) & ~(size_t)255;
    return p;
  };
  h16*  xpad   = (h16*) alloc((size_t)B_ * T_ * 32 * 2);
  h16*  l1in   = (h16*) alloc((size_t)T_ * B_ * 1024 * 2);
  h16*  encout = (h16*) alloc((size_t)B_ * T_ * 1024 * 2);
  h16*  WaV    = (h16*) alloc((size_t)B_ * T_ * H_ * 2);
  float* cdump = (float*)alloc((size_t)2 * B_ * H_ * 4);
  float* score = (float*)alloc((size_t)B_ * T_ * 4);
  float* qUa   = (float*)alloc((size_t)B_ * H_ * 4);
  h16*  xcat   = (h16*) alloc((size_t)B_ * 1056 * 2);
  h16*  dh0    = (h16*) alloc((size_t)2 * B_ * H_ * 2);
  h16*  dh1    = (h16*) alloc((size_t)2 * B_ * H_ * 2);
  u32*  slots  = (u32*) alloc((size_t)2 * 256 * 32 * 4);   // [0]: encoder, [1]: decoder
  h16*  bWih0  = (h16*) alloc((size_t)2 * 2048 * 32 * 2);
  h16*  bWhh0  = (h16*) alloc((size_t)2 * 2048 * 512 * 2);
  h16*  bWih1  = (h16*) alloc((size_t)2 * 2048 * 1024 * 2);
  h16*  bWhh1  = (h16*) alloc((size_t)2 * 2048 * 512 * 2);
  h16*  bdWih0 = (h16*) alloc((size_t)2048 * 1056 * 2);
  h16*  bdWhh0 = (h16*) alloc((size_t)2048 * 512 * 2);
  h16*  bdWih1 = (h16*) alloc((size_t)2048 * 512 * 2);
  h16*  bdWhh1 = (h16*) alloc((size_t)2048 * 512 * 2);
  h16*  bWa    = (h16*) alloc((size_t)512 * 1024 * 2);
  h16*  bUa    = (h16*) alloc((size_t)512 * 512 * 2);
  h16*  bprojW = (h16*) alloc((size_t)512 * 512 * 2);
  if (cur > ws_size) return;

  (void)hipMemsetAsync(slots, 0, (size_t)2 * 256 * 32 * 4, stream);
  (void)hipMemsetAsync(xcat, 0, (size_t)B_ * 1056 * 2, stream);

  auto conv = [&](const float* in, h16* o, int rows, int kin, int kout) {
    const size_t total = (size_t)rows * kout;
    convert_pad<<<dim3((unsigned)((total + 255) / 256)), dim3(256), 0, stream>>>(in, o, rows, kin, kout);
  };
  conv(x,     xpad,   B_ * T_,  8,    32);
  conv(eWih0, bWih0,  2 * 2048, 8,    32);
  conv(eWhh0, bWhh0,  2 * 2048, 512,  512);
  conv(eWih1, bWih1,  2 * 2048, 1024, 1024);
  conv(eWhh1, bWhh1,  2 * 2048, 512,  512);
  conv(dWih0, bdWih0, 2048,     1026, 1056);
  conv(dWhh0, bdWhh0, 2048,     512,  512);
  conv(dWih1, bdWih1, 2048,     512,  512);
  conv(dWhh1, bdWhh1, 2048,     512,  512);
  conv(Wa,    bWa,    512,      1024, 1024);
  conv(Ua,    bUa,    512,      512,  512);
  conv(projW, bprojW, 512,      512,  512);

  // ---- encoder: one persistent kernel ----
  EncP P;
  P.xpad = xpad; P.Wih0 = bWih0; P.Whh0 = bWhh0; P.Wih1 = bWih1; P.Whh1 = bWhh1;
  P.b0 = eb0; P.b1 = eb1; P.l1in = l1in; P.encout = encout; P.cdump = cdump; P.slots = slots;
  encoder_persist<<<dim3(256), dim3(512), 0, stream>>>(P);

  // ---- Wa_vals + decoder h init ----
  gemm_tn<<<dim3(B_ * T_ / 64, 8), dim3(256), 0, stream>>>(encout, 1024, bWa, nullptr, WaV, 512, 1024, 1);
  gemm_tn<<<dim3(B_ / 64, 8), dim3(256), 0, stream>>>(l1in + (size_t)(T_ - 1) * B_ * 1024, 1024,
                                                      bprojW, projb, dh0, 512, 512, 2);
  gemm_tn<<<dim3(B_ / 64, 8), dim3(256), 0, stream>>>(l1in + 512, 1024,
                                                      bprojW, projb, dh1, 512, 512, 2);
  y0_init<<<dim3(1), dim3(256), 0, stream>>>(x, xcat);

  // ---- decoder: one persistent kernel ----
  DecP D;
  D.bUa = bUa; D.WaV = WaV; D.enc = encout;
  D.bdWih0 = bdWih0; D.bdWhh0 = bdWhh0; D.bdWih1 = bdWih1; D.bdWhh1 = bdWhh1;
  D.Va = Va; D.db0 = db0; D.db1 = db1; D.fcW = fcW; D.fcb = fcb; D.cdump = cdump;
  D.qUa = qUa; D.score = score; D.out = out;
  D.xcat = xcat; D.dh0 = dh0; D.dh1 = dh1;
  D.slots = slots + 256 * 32;
  decoder_persist<<<dim3(256), dim3(512), 0, stream>>>(D);
}